// Round 12
// baseline (80.927 us; speedup 1.0000x reference)
//
#include <hip/hip_runtime.h>
#include <hip/hip_fp16.h>
#include <hip/hip_bf16.h>

#define NL 26
#define ND 128
#define NT 64
#define NB 8192
#define NIPB 32   // items per block
#define ITP 34    // padded item stride

typedef __attribute__((ext_vector_type(8))) short bf16x8;
typedef __attribute__((ext_vector_type(4))) float f32x4;

__device__ __forceinline__ uint32_t pk_bf16(float lo, float hi) {
    uint32_t r;
    asm("v_cvt_pk_bf16_f32 %0, %1, %2" : "=v"(r) : "v"(lo), "v"(hi));
    return r;
}

// ---------------------------------------------------------------------------
// Producer/consumer fused kernel. Block = 512 thr (8 waves), 32 items,
// grid = 256 = 1 block/CU (LDS ~153 KB pins it).
//  Round-12 changes vs round 11 (DP/emission arithmetic identical):
//   * Y preloaded to LDS once per block (8 KB) -> no global access (and no
//     latency stall) inside the producer tile loop.
//   * Tiles (slab-major, 0..127) split contiguously across the 7 producers
//     (18-19 each, was 16-20) -> balanced issue rate; per-tile ready-count
//     (consumer waits for 32 per slab).
//   * gold accumulated into per-(item,slab) slots (unique writer, no race),
//     consumer sums slots in fixed order -> deterministic.
// ---------------------------------------------------------------------------
__global__ __launch_bounds__(512, 2) void crf_fused(
    const float* __restrict__ X, const int* __restrict__ Y,
    const float* __restrict__ P, float* __restrict__ partials)
{
    __shared__ float TrS[NL * NL];                    // 2704 B
    __shared__ __half emT[NT][32][ITP];               // 139264 B
    __shared__ alignas(16) uint32_t pScr[2][16][20];  // 2560 B
    __shared__ alignas(16) float goldS2[NIPB][4];     // 512 B
    __shared__ alignas(16) int yS[NIPB][NT];          // 8192 B
    __shared__ int ready[4];

    const int tid = threadIdx.x;
    if (tid < 4) ready[tid] = 0;
    for (int k = tid; k < NL * NL; k += 512) TrS[k] = P[NL * ND + k];
    // Y -> LDS, one int4 per thread (512 * 16B = 8KB)
    {
        const int4* Y4 = reinterpret_cast<const int4*>(Y + (size_t)blockIdx.x * NIPB * NT);
        reinterpret_cast<int4*>(&yS[0][0])[tid] = Y4[tid];
    }
    __syncthreads();

    const int warp = tid >> 6;   // 0..7
    const int lane = tid & 63;
    const int r16  = lane & 15;
    const int kq   = lane >> 4;
    const int item0 = blockIdx.x * NIPB;

    if (warp > 0) {
        // ================= producers (waves 1..7) =================
        bf16x8 Bf[2][4];
        #pragma unroll
        for (int h = 0; h < 2; ++h) {
            int n = r16 + 16 * h;
            #pragma unroll
            for (int kb = 0; kb < 4; ++kb) {
                float w[8];
                if (n < NL) {
                    const float4* wp = reinterpret_cast<const float4*>(P + n * ND + kb * 32 + kq * 8);
                    float4 w0 = wp[0], w1 = wp[1];
                    w[0]=w0.x; w[1]=w0.y; w[2]=w0.z; w[3]=w0.w;
                    w[4]=w1.x; w[5]=w1.y; w[6]=w1.z; w[7]=w1.w;
                } else {
                    #pragma unroll
                    for (int jj = 0; jj < 8; ++jj) w[jj] = 0.f;
                }
                union { uint32_t u[4]; bf16x8 v; } pk;
                pk.u[0] = pk_bf16(w[0], w[1]); pk.u[1] = pk_bf16(w[2], w[3]);
                pk.u[2] = pk_bf16(w[4], w[5]); pk.u[3] = pk_bf16(w[6], w[7]);
                Bf[h][kb] = pk.v;
            }
        }

        const float4* X4 = reinterpret_cast<const float4*>(X);
        // contiguous tile range, slab-major: g in [g0,g1), it = g&31, s = g>>5
        const int g0 = ((warp - 1) * 128) / 7;
        const int g1 = (warp * 128) / 7;

        auto tile_load = [&](int g, float4 (*xa)[2]) {
            int it = g & 31, s = g >> 5;
            size_t row  = (size_t)(item0 + it) * NT + s * 16 + r16;
            size_t base = row * 32 + kq * 2;
            #pragma unroll
            for (int kb = 0; kb < 4; ++kb) {
                xa[kb][0] = X4[base + kb * 8];
                xa[kb][1] = X4[base + kb * 8 + 1];
            }
        };
        auto tile_comp = [&](int g, float4 (*xa)[2]) {
            int it = g & 31, s = g >> 5;
            f32x4 acc0 = {0.f,0.f,0.f,0.f}, acc1 = {0.f,0.f,0.f,0.f};
            #pragma unroll
            for (int kb = 0; kb < 4; ++kb) {
                union { uint32_t u[4]; bf16x8 v; } A;
                A.u[0] = pk_bf16(xa[kb][0].x, xa[kb][0].y);
                A.u[1] = pk_bf16(xa[kb][0].z, xa[kb][0].w);
                A.u[2] = pk_bf16(xa[kb][1].x, xa[kb][1].y);
                A.u[3] = pk_bf16(xa[kb][1].z, xa[kb][1].w);
                acc0 = __builtin_amdgcn_mfma_f32_16x16x32_bf16(A.v, Bf[0][kb], acc0, 0, 0, 0);
                acc1 = __builtin_amdgcn_mfma_f32_16x16x32_bf16(A.v, Bf[1][kb], acc1, 0, 0, 0);
            }
            // D layout: col = lane&15 = label, row = kq*4+q = t-offset  [m89]
            #pragma unroll
            for (int q = 0; q < 4; ++q) {
                int t = s * 16 + kq * 4 + q;
                emT[t][r16][it]      = __float2half(__expf(acc0[q]) * 0.0625f);
                emT[t][r16 + 16][it] = __float2half(__expf(acc1[q]) * 0.0625f);
            }
            // gold chunk (Y from LDS; unique writer per (it,s) -> no race)
            if (lane < 16) {
                const int* yrow = yS[it];
                int tg = s * 16 + lane;
                int yt = yrow[tg];
                float g2 = __logf(__half2float(emT[tg][yt][it]));
                if (tg < NT - 1) g2 += TrS[yt * NL + yrow[tg + 1]];
                #pragma unroll
                for (int mk = 8; mk >= 1; mk >>= 1) g2 += __shfl_xor(g2, mk);
                if (lane == 0) goldS2[it][s] = g2;
            }
            __threadfence_block();
            if (lane == 0) atomicAdd(&ready[s], 1);
        };

        // compile-time-named double buffers (rule #20)
        float4 xaA[4][2], xaB[4][2];
        int g = g0;
        tile_load(g, xaA);
        #pragma unroll 1
        for (; g + 2 <= g1; g += 2) {
            tile_load(g + 1, xaB);
            tile_comp(g, xaA);
            if (g + 2 < g1) tile_load(g + 2, xaA);
            tile_comp(g + 1, xaB);
        }
        if (g < g1) tile_comp(g, xaA);   // odd-count tail (already loaded)
        return;
    }

    // ================= consumer (wave 0) =================
    bf16x8 Ef[2];
    #pragma unroll
    for (int h = 0; h < 2; ++h) {
        int n = r16 + 16 * h;
        union { uint32_t u[4]; bf16x8 v; } c;
        #pragma unroll
        for (int w = 0; w < 4; ++w) {
            int sl = kq * 4 + w;
            float lo = (n < NL) ? __expf(TrS[sl * NL + n]) : 0.f;
            float hi = (n < NL && sl + 16 < NL) ? __expf(TrS[(sl + 16) * NL + n]) : 0.f;
            c.u[w] = pk_bf16(lo, hi);
        }
        Ef[h] = c.v;
    }

    bf16x8 pfA, pfB;
    float M[2][4] = {{0.f,0.f,0.f,0.f},{0.f,0.f,0.f,0.f}};
    float pn0[2][4], pn1[2][4];
    const f32x4 zacc = {0.f, 0.f, 0.f, 0.f};

    #pragma unroll 1
    for (int s = 0; s < 4; ++s) {
        volatile int* rp = (volatile int*)&ready[s];
        while (*rp < 32) __builtin_amdgcn_s_sleep(8);
        __threadfence_block();

        int t = s * 16;
        if (s == 0) {
            union { uint32_t u[4]; bf16x8 v; } c;
            #pragma unroll
            for (int w = 0; w < 4; ++w) {
                int sl = kq * 4 + w;
                float lo = __half2float(emT[0][sl][r16]);
                float hi = (sl + 16 < NL) ? __half2float(emT[0][sl + 16][r16]) : 0.f;
                c.u[w] = pk_bf16(lo, hi);
            }
            pfA = c.v;
            #pragma unroll
            for (int w = 0; w < 4; ++w) {
                int sl = kq * 4 + w;
                float lo = __half2float(emT[0][sl][16 + r16]);
                float hi = (sl + 16 < NL) ? __half2float(emT[0][sl + 16][16 + r16]) : 0.f;
                c.u[w] = pk_bf16(lo, hi);
            }
            pfB = c.v;
            t = 1;
        }
        const int tend = s * 16 + 16;
        #pragma unroll 1
        for (; t < tend; ++t) {
            f32x4 dA0 = __builtin_amdgcn_mfma_f32_16x16x32_bf16(pfA, Ef[0], zacc, 0, 0, 0);
            f32x4 dA1 = __builtin_amdgcn_mfma_f32_16x16x32_bf16(pfA, Ef[1], zacc, 0, 0, 0);
            f32x4 dB0 = __builtin_amdgcn_mfma_f32_16x16x32_bf16(pfB, Ef[0], zacc, 0, 0, 0);
            f32x4 dB1 = __builtin_amdgcn_mfma_f32_16x16x32_bf16(pfB, Ef[1], zacc, 0, 0, 0);
            #pragma unroll
            for (int g = 0; g < 2; ++g) {
                const f32x4& d0 = g ? dB0 : dA0;
                const f32x4& d1 = g ? dB1 : dA1;
                const __half2* pe0p = reinterpret_cast<const __half2*>(&emT[t][r16][g * 16 + kq * 4]);
                const __half2* pe1p = reinterpret_cast<const __half2*>(&emT[t][r16 + 16][g * 16 + kq * 4]);
                __half2 pe0a = pe0p[0], pe0b = pe0p[1];
                __half2 pe1a = pe1p[0], pe1b = pe1p[1];
                pn0[g][0] = d0[0] * __low2float(pe0a);  pn0[g][1] = d0[1] * __high2float(pe0a);
                pn0[g][2] = d0[2] * __low2float(pe0b);  pn0[g][3] = d0[3] * __high2float(pe0b);
                pn1[g][0] = d1[0] * __low2float(pe1a);  pn1[g][1] = d1[1] * __high2float(pe1a);
                pn1[g][2] = d1[2] * __low2float(pe1b);  pn1[g][3] = d1[3] * __high2float(pe1b);

                if ((t & 3) == 0) {                    // renorm every 4 steps
                    #pragma unroll
                    for (int q = 0; q < 4; ++q) {
                        float m = fmaxf(pn0[g][q], pn1[g][q]);
                        m = fmaxf(m, __shfl_xor(m, 1));
                        m = fmaxf(m, __shfl_xor(m, 2));
                        m = fmaxf(m, __shfl_xor(m, 4));
                        m = fmaxf(m, __shfl_xor(m, 8));
                        float r = __builtin_amdgcn_rcpf(m);
                        pn0[g][q] *= r; pn1[g][q] *= r;
                        M[g][q] += __logf(m);
                    }
                }
                #pragma unroll
                for (int q = 0; q < 4; ++q)
                    pScr[g][kq * 4 + q][r16] = pk_bf16(pn0[g][q], pn1[g][q]);
            }
            uint4 pwA = *reinterpret_cast<const uint4*>(&pScr[0][r16][kq * 4]);
            uint4 pwB = *reinterpret_cast<const uint4*>(&pScr[1][r16][kq * 4]);
            union { uint4 u; bf16x8 v; } pc;
            pc.u = pwA; pfA = pc.v;
            pc.u = pwB; pfB = pc.v;
        }
    }

    // ---- epilogue: per-item logZ + gold (slot sum in fixed order) ----
    float tot = 0.f;
    #pragma unroll
    for (int g = 0; g < 2; ++g) {
        #pragma unroll
        for (int q = 0; q < 4; ++q) {
            float ssum = pn0[g][q] + pn1[g][q];
            ssum += __shfl_xor(ssum, 1);
            ssum += __shfl_xor(ssum, 2);
            ssum += __shfl_xor(ssum, 4);
            ssum += __shfl_xor(ssum, 8);
            float logZ = M[g][q] + __logf(ssum);
            int it = g * 16 + kq * 4 + q;
            float4 gs = *reinterpret_cast<const float4*>(&goldS2[it][0]);
            float gold = ((gs.x + gs.y) + (gs.z + gs.w));
            tot += gold - logZ;                        // 1/16 scales cancel
        }
    }
    tot += __shfl_xor(tot, 16);
    tot += __shfl_xor(tot, 32);
    if (lane == 0) partials[blockIdx.x] = tot;
}

__global__ void crf_reduce2(const float* __restrict__ partials,
                            float* __restrict__ out, int n) {
    __shared__ float red[256];
    float s = 0.f;
    for (int i = threadIdx.x; i < n; i += 256) s += partials[i];
    red[threadIdx.x] = s;
    __syncthreads();
    for (int k = 128; k >= 1; k >>= 1) {
        if ((int)threadIdx.x < k) red[threadIdx.x] += red[threadIdx.x + k];
        __syncthreads();
    }
    if (threadIdx.x == 0) out[0] = -red[0] / (float)NB;
}

extern "C" void kernel_launch(void* const* d_in, const int* in_sizes, int n_in,
                              void* d_out, int out_size, void* d_ws, size_t ws_size,
                              hipStream_t stream) {
    const float* X = (const float*)d_in[0];
    const int*   Y = (const int*)d_in[1];
    const float* P = (const float*)d_in[2];
    float* out = (float*)d_out;
    float* partials = (float*)d_ws;   // 256 floats

    crf_fused<<<NB / NIPB, 512, 0, stream>>>(X, Y, P, partials);
    crf_reduce2<<<1, 256, 0, stream>>>(partials, out, NB / NIPB);
}

// Round 13
// 65.810 us; speedup vs baseline: 1.2297x; 1.2297x over previous
//
#include <hip/hip_runtime.h>
#include <hip/hip_fp16.h>
#include <hip/hip_bf16.h>

#define NL 26
#define ND 128
#define NT 64
#define NB 8192
#define NIPB 16   // items per block
#define ITP 18    // padded item stride (bank step 9 -> 16 distinct banks)

typedef __attribute__((ext_vector_type(8))) short bf16x8;
typedef __attribute__((ext_vector_type(4))) float f32x4;

__device__ __forceinline__ uint32_t pk_bf16(float lo, float hi) {
    uint32_t r;
    asm("v_cvt_pk_bf16_f32 %0, %1, %2" : "=v"(r) : "v"(lo), "v"(hi));
    return r;
}

// ---------------------------------------------------------------------------
// Producer/consumer fused kernel (round-8 structure, measured best 70.9us).
// Block = 256 thr (4 waves), 16 items, LDS ~78KB -> 2 blocks/CU.
//  Round-13 deltas vs round 8 (DP/emission arithmetic identical):
//   * balanced producer split: (6,5,5) rotated per slab -> totals (22,21,21)
//     tiles/wave (was 24/20/20). Signaling stays per-slab (4 fences/wave;
//     round-12's per-TILE fence drained the prefetch pipeline = regression).
//   * emT item stride 16 -> 18: ds_write banks spread 4 -> 16 (was 16-way
//     conflict), ~free 4-way remains.
// ---------------------------------------------------------------------------
__global__ __launch_bounds__(256, 2) void crf_fused(
    const float* __restrict__ X, const int* __restrict__ Y,
    const float* __restrict__ P, float* __restrict__ partials)
{
    __shared__ float TrS[NL * NL];                    // 2704 B
    __shared__ __half emT[NT][32][ITP];               // 73728 B
    __shared__ alignas(16) uint32_t pScr[16][20];     // 1280 B
    __shared__ int ready[4];

    const int tid = threadIdx.x;
    if (tid < 4) ready[tid] = 0;
    for (int k = tid; k < NL * NL; k += 256) TrS[k] = P[NL * ND + k];
    __syncthreads();

    const int warp = tid >> 6;
    const int lane = tid & 63;
    const int r16  = lane & 15;
    const int kq   = lane >> 4;
    const int item0 = blockIdx.x * NIPB;

    if (warp > 0) {
        // ================= producers (waves 1..3) =================
        bf16x8 Bf[2][4];
        #pragma unroll
        for (int h = 0; h < 2; ++h) {
            int n = r16 + 16 * h;
            #pragma unroll
            for (int kb = 0; kb < 4; ++kb) {
                float w[8];
                if (n < NL) {
                    const float4* wp = reinterpret_cast<const float4*>(P + n * ND + kb * 32 + kq * 8);
                    float4 w0 = wp[0], w1 = wp[1];
                    w[0]=w0.x; w[1]=w0.y; w[2]=w0.z; w[3]=w0.w;
                    w[4]=w1.x; w[5]=w1.y; w[6]=w1.z; w[7]=w1.w;
                } else {
                    #pragma unroll
                    for (int jj = 0; jj < 8; ++jj) w[jj] = 0.f;
                }
                union { uint32_t u[4]; bf16x8 v; } pk;
                pk.u[0] = pk_bf16(w[0], w[1]); pk.u[1] = pk_bf16(w[2], w[3]);
                pk.u[2] = pk_bf16(w[4], w[5]); pk.u[3] = pk_bf16(w[6], w[7]);
                Bf[h][kb] = pk.v;
            }
        }

        const float4* X4 = reinterpret_cast<const float4*>(X);
        const int w = warp - 1;   // 0..2
        // cnt(w,s) = 6 if w == s%3 else 5; beg = prefix over waves (scalars only)
        const int c0 = (w == 0) ? 6 : 5, c1 = (w == 1) ? 6 : 5;
        const int c2 = (w == 2) ? 6 : 5, c3 = (w == 0) ? 6 : 5;
        const int p1 = c0, p2 = c0 + c1, p3 = c0 + c1 + c2;
        const int total = p3 + c3;                       // 22 or 21
        const int beg0 = (w == 0) ? 0 : (w == 1) ? 6 : 11;
        const int beg1 = (w == 0) ? 0 : (w == 1) ? 5 : 11;
        const int beg2 = (w == 0) ? 0 : (w == 1) ? 5 : 10;
        const int beg3 = beg0;

        auto map_it = [&](int i, int& it, int& s) {
            if (i < p1)      { s = 0; it = beg0 + i; }
            else if (i < p2) { s = 1; it = beg1 + (i - p1); }
            else if (i < p3) { s = 2; it = beg2 + (i - p2); }
            else             { s = 3; it = beg3 + (i - p3); }
        };
        auto tile_load = [&](int i, float4 (*xa)[2]) {
            int it, s; map_it(i, it, s);
            size_t row  = (size_t)(item0 + it) * NT + s * 16 + r16;
            size_t base = row * 32 + kq * 2;
            #pragma unroll
            for (int kb = 0; kb < 4; ++kb) {
                xa[kb][0] = X4[base + kb * 8];
                xa[kb][1] = X4[base + kb * 8 + 1];
            }
        };
        auto tile_comp = [&](int i, float4 (*xa)[2]) {
            int it, s; map_it(i, it, s);
            f32x4 acc0 = {0.f,0.f,0.f,0.f}, acc1 = {0.f,0.f,0.f,0.f};
            #pragma unroll
            for (int kb = 0; kb < 4; ++kb) {
                union { uint32_t u[4]; bf16x8 v; } A;
                A.u[0] = pk_bf16(xa[kb][0].x, xa[kb][0].y);
                A.u[1] = pk_bf16(xa[kb][0].z, xa[kb][0].w);
                A.u[2] = pk_bf16(xa[kb][1].x, xa[kb][1].y);
                A.u[3] = pk_bf16(xa[kb][1].z, xa[kb][1].w);
                acc0 = __builtin_amdgcn_mfma_f32_16x16x32_bf16(A.v, Bf[0][kb], acc0, 0, 0, 0);
                acc1 = __builtin_amdgcn_mfma_f32_16x16x32_bf16(A.v, Bf[1][kb], acc1, 0, 0, 0);
            }
            // D layout: col = lane&15 = label, row = kq*4+q = t-offset  [m89]
            #pragma unroll
            for (int q = 0; q < 4; ++q) {
                int t = s * 16 + kq * 4 + q;
                emT[t][r16][it]      = __float2half(__expf(acc0[q]) * 0.0625f);
                emT[t][r16 + 16][it] = __float2half(__expf(acc1[q]) * 0.0625f);
            }
            // per-SLAB signal only (round-12 lesson: per-tile fence drains prefetch)
            if (i == p1 - 1 || i == p2 - 1 || i == p3 - 1 || i == total - 1) {
                __threadfence_block();
                if (lane == 0) atomicAdd(&ready[s], 1);
            }
        };

        // compile-time-named double buffers (rule #20)
        float4 xaA[4][2], xaB[4][2];
        int i = 0;
        tile_load(0, xaA);
        #pragma unroll 1
        for (; i + 2 <= total; i += 2) {
            tile_load(i + 1, xaB);
            tile_comp(i, xaA);
            if (i + 2 < total) tile_load(i + 2, xaA);
            tile_comp(i + 1, xaB);
        }
        if (i < total) tile_comp(i, xaA);   // odd-total tail (already loaded)
        return;
    }

    // ================= consumer (wave 0) =================
    bf16x8 Ef[2];
    #pragma unroll
    for (int h = 0; h < 2; ++h) {
        int n = r16 + 16 * h;
        union { uint32_t u[4]; bf16x8 v; } c;
        #pragma unroll
        for (int w = 0; w < 4; ++w) {
            int sl = kq * 4 + w;
            float lo = (n < NL) ? __expf(TrS[sl * NL + n]) : 0.f;
            float hi = (n < NL && sl + 16 < NL) ? __expf(TrS[(sl + 16) * NL + n]) : 0.f;
            c.u[w] = pk_bf16(lo, hi);
        }
        Ef[h] = c.v;
    }

    const int* yb = Y + (size_t)(item0 + r16) * NT;   // this lane's gold item
    float gold = 0.f;
    float M[4] = {0.f, 0.f, 0.f, 0.f};
    float pn0[4], pn1[4];
    bf16x8 pfrag;
    const f32x4 zacc = {0.f, 0.f, 0.f, 0.f};

    #pragma unroll 1
    for (int s = 0; s < 4; ++s) {
        volatile int* rp = (volatile int*)&ready[s];
        while (*rp < 3) __builtin_amdgcn_s_sleep(4);
        __threadfence_block();

        // ---- gold chunk: item r16, t = s*16 + kq*4 + e ----
        {
            int tb = s * 16 + kq * 4;
            int4 a = *reinterpret_cast<const int4*>(yb + tb);
            int ynext = (tb + 4 < NT) ? yb[tb + 4] : 0;
            int ys[5] = {a.x, a.y, a.z, a.w, ynext};
            #pragma unroll
            for (int e = 0; e < 4; ++e) {
                int t = tb + e;
                gold += __logf(__half2float(emT[t][ys[e]][r16]));
                if (t < NT - 1) gold += TrS[ys[e] * NL + ys[e + 1]];
            }
        }

        // ---- DP steps for this slab ----
        int t = s * 16;
        if (s == 0) {
            union { uint32_t u[4]; bf16x8 v; } c;
            #pragma unroll
            for (int w = 0; w < 4; ++w) {
                int sl = kq * 4 + w;
                float lo = __half2float(emT[0][sl][r16]);
                float hi = (sl + 16 < NL) ? __half2float(emT[0][sl + 16][r16]) : 0.f;
                c.u[w] = pk_bf16(lo, hi);
            }
            pfrag = c.v;
            t = 1;
        }
        const int tend = s * 16 + 16;
        #pragma unroll 1
        for (; t < tend; ++t) {
            f32x4 d0 = __builtin_amdgcn_mfma_f32_16x16x32_bf16(pfrag, Ef[0], zacc, 0, 0, 0);
            f32x4 d1 = __builtin_amdgcn_mfma_f32_16x16x32_bf16(pfrag, Ef[1], zacc, 0, 0, 0);
            const __half2* pe0p = reinterpret_cast<const __half2*>(&emT[t][r16][kq * 4]);
            const __half2* pe1p = reinterpret_cast<const __half2*>(&emT[t][r16 + 16][kq * 4]);
            __half2 pe0a = pe0p[0], pe0b = pe0p[1];
            __half2 pe1a = pe1p[0], pe1b = pe1p[1];
            pn0[0] = d0[0] * __low2float(pe0a);  pn0[1] = d0[1] * __high2float(pe0a);
            pn0[2] = d0[2] * __low2float(pe0b);  pn0[3] = d0[3] * __high2float(pe0b);
            pn1[0] = d1[0] * __low2float(pe1a);  pn1[1] = d1[1] * __high2float(pe1a);
            pn1[2] = d1[2] * __low2float(pe1b);  pn1[3] = d1[3] * __high2float(pe1b);

            if ((t & 3) == 0) {                    // renorm every 4 steps
                #pragma unroll
                for (int q = 0; q < 4; ++q) {
                    float m = fmaxf(pn0[q], pn1[q]);
                    m = fmaxf(m, __shfl_xor(m, 1));
                    m = fmaxf(m, __shfl_xor(m, 2));
                    m = fmaxf(m, __shfl_xor(m, 4));
                    m = fmaxf(m, __shfl_xor(m, 8));
                    float r = __builtin_amdgcn_rcpf(m);
                    pn0[q] *= r; pn1[q] *= r;
                    M[q] += __logf(m);
                }
            }
            // repack to next A-frag via LDS transpose
            #pragma unroll
            for (int q = 0; q < 4; ++q)
                pScr[kq * 4 + q][r16] = pk_bf16(pn0[q], pn1[q]);
            uint4 pw = *reinterpret_cast<const uint4*>(&pScr[r16][kq * 4]);
            union { uint4 u; bf16x8 v; } pc; pc.u = pw;
            pfrag = pc.v;
        }
    }

    // ---- epilogue: per-item logZ, combine with gold ----
    gold += __shfl_xor(gold, 16);
    gold += __shfl_xor(gold, 32);          // every lane: gold[item = r16]

    float tot = 0.f;
    #pragma unroll
    for (int q = 0; q < 4; ++q) {
        float ssum = pn0[q] + pn1[q];
        ssum += __shfl_xor(ssum, 1);
        ssum += __shfl_xor(ssum, 2);
        ssum += __shfl_xor(ssum, 4);
        ssum += __shfl_xor(ssum, 8);
        float logZ = M[q] + __logf(ssum);
        tot += __shfl(gold, kq * 4 + q) - logZ;   // 1/16 scales cancel exactly
    }
    tot += __shfl_xor(tot, 16);
    tot += __shfl_xor(tot, 32);
    if (lane == 0) partials[blockIdx.x] = tot;
}

__global__ void crf_reduce2(const float* __restrict__ partials,
                            float* __restrict__ out, int n) {
    __shared__ float red[256];
    float s = 0.f;
    for (int i = threadIdx.x; i < n; i += 256) s += partials[i];
    red[threadIdx.x] = s;
    __syncthreads();
    for (int k = 128; k >= 1; k >>= 1) {
        if ((int)threadIdx.x < k) red[threadIdx.x] += red[threadIdx.x + k];
        __syncthreads();
    }
    if (threadIdx.x == 0) out[0] = -red[0] / (float)NB;
}

extern "C" void kernel_launch(void* const* d_in, const int* in_sizes, int n_in,
                              void* d_out, int out_size, void* d_ws, size_t ws_size,
                              hipStream_t stream) {
    const float* X = (const float*)d_in[0];
    const int*   Y = (const int*)d_in[1];
    const float* P = (const float*)d_in[2];
    float* out = (float*)d_out;
    float* partials = (float*)d_ws;   // 512 floats

    crf_fused<<<NB / NIPB, 256, 0, stream>>>(X, Y, P, partials);
    crf_reduce2<<<1, 256, 0, stream>>>(partials, out, NB / NIPB);
}

// Round 14
// 64.966 us; speedup vs baseline: 1.2457x; 1.0130x over previous
//
#include <hip/hip_runtime.h>
#include <hip/hip_fp16.h>
#include <hip/hip_bf16.h>

#define NL 26
#define ND 128
#define NT 64
#define NB 8192
#define NIPB 16   // items per block
#define ITP 18    // padded item stride (bank step 9 -> 16 distinct banks)

typedef __attribute__((ext_vector_type(8))) short bf16x8;
typedef __attribute__((ext_vector_type(4))) float f32x4;

__device__ __forceinline__ uint32_t pk_bf16(float lo, float hi) {
    uint32_t r;
    asm("v_cvt_pk_bf16_f32 %0, %1, %2" : "=v"(r) : "v"(lo), "v"(hi));
    return r;
}

// ---------------------------------------------------------------------------
// Producer/consumer fused kernel. Block = 320 thr (5 waves): 4 producers +
// 1 consumer; 16 items; LDS ~78KB -> 2 blocks/CU -> 8 streaming waves/CU
// (round 13 had 6; stream rate tracks streaming-wave count).
// 64 tiles / 4 producers = 16 each, perfectly balanced; wave w owns items
// w*4..w*4+3 of every slab; per-slab ready-count to 4.
// Consumer/DP/gold arithmetic identical to round 13 (absmax ~2 expected).
// ---------------------------------------------------------------------------
__global__ __launch_bounds__(320, 2) void crf_fused(
    const float* __restrict__ X, const int* __restrict__ Y,
    const float* __restrict__ P, float* __restrict__ partials)
{
    __shared__ float TrS[NL * NL];                    // 2704 B
    __shared__ __half emT[NT][32][ITP];               // 73728 B
    __shared__ alignas(16) uint32_t pScr[16][20];     // 1280 B
    __shared__ int ready[4];

    const int tid = threadIdx.x;
    if (tid < 4) ready[tid] = 0;
    for (int k = tid; k < NL * NL; k += 320) TrS[k] = P[NL * ND + k];
    __syncthreads();

    const int warp = tid >> 6;   // 0..4
    const int lane = tid & 63;
    const int r16  = lane & 15;
    const int kq   = lane >> 4;
    const int item0 = blockIdx.x * NIPB;

    if (warp > 0) {
        // ================= producers (waves 1..4) =================
        bf16x8 Bf[2][4];
        #pragma unroll
        for (int h = 0; h < 2; ++h) {
            int n = r16 + 16 * h;
            #pragma unroll
            for (int kb = 0; kb < 4; ++kb) {
                float w[8];
                if (n < NL) {
                    const float4* wp = reinterpret_cast<const float4*>(P + n * ND + kb * 32 + kq * 8);
                    float4 w0 = wp[0], w1 = wp[1];
                    w[0]=w0.x; w[1]=w0.y; w[2]=w0.z; w[3]=w0.w;
                    w[4]=w1.x; w[5]=w1.y; w[6]=w1.z; w[7]=w1.w;
                } else {
                    #pragma unroll
                    for (int jj = 0; jj < 8; ++jj) w[jj] = 0.f;
                }
                union { uint32_t u[4]; bf16x8 v; } pk;
                pk.u[0] = pk_bf16(w[0], w[1]); pk.u[1] = pk_bf16(w[2], w[3]);
                pk.u[2] = pk_bf16(w[4], w[5]); pk.u[3] = pk_bf16(w[6], w[7]);
                Bf[h][kb] = pk.v;
            }
        }

        const float4* X4 = reinterpret_cast<const float4*>(X);
        const int w = warp - 1;   // 0..3: owns items w*4..w*4+3 of every slab

        // tile index i in 0..15: s = i>>2, item = w*4 + (i&3)
        auto tile_load = [&](int i, float4 (*xa)[2]) {
            int s = i >> 2, it = w * 4 + (i & 3);
            size_t row  = (size_t)(item0 + it) * NT + s * 16 + r16;
            size_t base = row * 32 + kq * 2;
            #pragma unroll
            for (int kb = 0; kb < 4; ++kb) {
                xa[kb][0] = X4[base + kb * 8];
                xa[kb][1] = X4[base + kb * 8 + 1];
            }
        };
        auto tile_comp = [&](int i, float4 (*xa)[2]) {
            int s = i >> 2, it = w * 4 + (i & 3);
            f32x4 acc0 = {0.f,0.f,0.f,0.f}, acc1 = {0.f,0.f,0.f,0.f};
            #pragma unroll
            for (int kb = 0; kb < 4; ++kb) {
                union { uint32_t u[4]; bf16x8 v; } A;
                A.u[0] = pk_bf16(xa[kb][0].x, xa[kb][0].y);
                A.u[1] = pk_bf16(xa[kb][0].z, xa[kb][0].w);
                A.u[2] = pk_bf16(xa[kb][1].x, xa[kb][1].y);
                A.u[3] = pk_bf16(xa[kb][1].z, xa[kb][1].w);
                acc0 = __builtin_amdgcn_mfma_f32_16x16x32_bf16(A.v, Bf[0][kb], acc0, 0, 0, 0);
                acc1 = __builtin_amdgcn_mfma_f32_16x16x32_bf16(A.v, Bf[1][kb], acc1, 0, 0, 0);
            }
            // D layout: col = lane&15 = label, row = kq*4+q = t-offset  [m89]
            #pragma unroll
            for (int q = 0; q < 4; ++q) {
                int t = s * 16 + kq * 4 + q;
                emT[t][r16][it]      = __float2half(__expf(acc0[q]) * 0.0625f);
                emT[t][r16 + 16][it] = __float2half(__expf(acc1[q]) * 0.0625f);
            }
            // per-SLAB signal only (round-12 lesson: per-tile fence kills prefetch)
            if ((i & 3) == 3) {
                __threadfence_block();
                if (lane == 0) atomicAdd(&ready[s], 1);
            }
        };

        // compile-time-named double buffers (rule #20); 16 tiles, even count
        float4 xaA[4][2], xaB[4][2];
        tile_load(0, xaA);
        #pragma unroll 1
        for (int i = 0; i < 16; i += 2) {
            tile_load(i + 1, xaB);
            tile_comp(i, xaA);
            if (i + 2 < 16) tile_load(i + 2, xaA);
            tile_comp(i + 1, xaB);
        }
        return;
    }

    // ================= consumer (wave 0) =================
    bf16x8 Ef[2];
    #pragma unroll
    for (int h = 0; h < 2; ++h) {
        int n = r16 + 16 * h;
        union { uint32_t u[4]; bf16x8 v; } c;
        #pragma unroll
        for (int w = 0; w < 4; ++w) {
            int sl = kq * 4 + w;
            float lo = (n < NL) ? __expf(TrS[sl * NL + n]) : 0.f;
            float hi = (n < NL && sl + 16 < NL) ? __expf(TrS[(sl + 16) * NL + n]) : 0.f;
            c.u[w] = pk_bf16(lo, hi);
        }
        Ef[h] = c.v;
    }

    const int* yb = Y + (size_t)(item0 + r16) * NT;   // this lane's gold item
    float gold = 0.f;
    float M[4] = {0.f, 0.f, 0.f, 0.f};
    float pn0[4], pn1[4];
    bf16x8 pfrag;
    const f32x4 zacc = {0.f, 0.f, 0.f, 0.f};

    #pragma unroll 1
    for (int s = 0; s < 4; ++s) {
        volatile int* rp = (volatile int*)&ready[s];
        while (*rp < 4) __builtin_amdgcn_s_sleep(4);
        __threadfence_block();

        // ---- gold chunk: item r16, t = s*16 + kq*4 + e ----
        {
            int tb = s * 16 + kq * 4;
            int4 a = *reinterpret_cast<const int4*>(yb + tb);
            int ynext = (tb + 4 < NT) ? yb[tb + 4] : 0;
            int ys[5] = {a.x, a.y, a.z, a.w, ynext};
            #pragma unroll
            for (int e = 0; e < 4; ++e) {
                int t = tb + e;
                gold += __logf(__half2float(emT[t][ys[e]][r16]));
                if (t < NT - 1) gold += TrS[ys[e] * NL + ys[e + 1]];
            }
        }

        // ---- DP steps for this slab ----
        int t = s * 16;
        if (s == 0) {
            union { uint32_t u[4]; bf16x8 v; } c;
            #pragma unroll
            for (int w = 0; w < 4; ++w) {
                int sl = kq * 4 + w;
                float lo = __half2float(emT[0][sl][r16]);
                float hi = (sl + 16 < NL) ? __half2float(emT[0][sl + 16][r16]) : 0.f;
                c.u[w] = pk_bf16(lo, hi);
            }
            pfrag = c.v;
            t = 1;
        }
        const int tend = s * 16 + 16;
        #pragma unroll 1
        for (; t < tend; ++t) {
            f32x4 d0 = __builtin_amdgcn_mfma_f32_16x16x32_bf16(pfrag, Ef[0], zacc, 0, 0, 0);
            f32x4 d1 = __builtin_amdgcn_mfma_f32_16x16x32_bf16(pfrag, Ef[1], zacc, 0, 0, 0);
            const __half2* pe0p = reinterpret_cast<const __half2*>(&emT[t][r16][kq * 4]);
            const __half2* pe1p = reinterpret_cast<const __half2*>(&emT[t][r16 + 16][kq * 4]);
            __half2 pe0a = pe0p[0], pe0b = pe0p[1];
            __half2 pe1a = pe1p[0], pe1b = pe1p[1];
            pn0[0] = d0[0] * __low2float(pe0a);  pn0[1] = d0[1] * __high2float(pe0a);
            pn0[2] = d0[2] * __low2float(pe0b);  pn0[3] = d0[3] * __high2float(pe0b);
            pn1[0] = d1[0] * __low2float(pe1a);  pn1[1] = d1[1] * __high2float(pe1a);
            pn1[2] = d1[2] * __low2float(pe1b);  pn1[3] = d1[3] * __high2float(pe1b);

            if ((t & 3) == 0) {                    // renorm every 4 steps
                #pragma unroll
                for (int q = 0; q < 4; ++q) {
                    float m = fmaxf(pn0[q], pn1[q]);
                    m = fmaxf(m, __shfl_xor(m, 1));
                    m = fmaxf(m, __shfl_xor(m, 2));
                    m = fmaxf(m, __shfl_xor(m, 4));
                    m = fmaxf(m, __shfl_xor(m, 8));
                    float r = __builtin_amdgcn_rcpf(m);
                    pn0[q] *= r; pn1[q] *= r;
                    M[q] += __logf(m);
                }
            }
            // repack to next A-frag via LDS transpose
            #pragma unroll
            for (int q = 0; q < 4; ++q)
                pScr[kq * 4 + q][r16] = pk_bf16(pn0[q], pn1[q]);
            uint4 pw = *reinterpret_cast<const uint4*>(&pScr[r16][kq * 4]);
            union { uint4 u; bf16x8 v; } pc; pc.u = pw;
            pfrag = pc.v;
        }
    }

    // ---- epilogue: per-item logZ, combine with gold ----
    gold += __shfl_xor(gold, 16);
    gold += __shfl_xor(gold, 32);          // every lane: gold[item = r16]

    float tot = 0.f;
    #pragma unroll
    for (int q = 0; q < 4; ++q) {
        float ssum = pn0[q] + pn1[q];
        ssum += __shfl_xor(ssum, 1);
        ssum += __shfl_xor(ssum, 2);
        ssum += __shfl_xor(ssum, 4);
        ssum += __shfl_xor(ssum, 8);
        float logZ = M[q] + __logf(ssum);
        tot += __shfl(gold, kq * 4 + q) - logZ;   // 1/16 scales cancel exactly
    }
    tot += __shfl_xor(tot, 16);
    tot += __shfl_xor(tot, 32);
    if (lane == 0) partials[blockIdx.x] = tot;
}

__global__ void crf_reduce2(const float* __restrict__ partials,
                            float* __restrict__ out, int n) {
    __shared__ float red[256];
    float s = 0.f;
    for (int i = threadIdx.x; i < n; i += 256) s += partials[i];
    red[threadIdx.x] = s;
    __syncthreads();
    for (int k = 128; k >= 1; k >>= 1) {
        if ((int)threadIdx.x < k) red[threadIdx.x] += red[threadIdx.x + k];
        __syncthreads();
    }
    if (threadIdx.x == 0) out[0] = -red[0] / (float)NB;
}

extern "C" void kernel_launch(void* const* d_in, const int* in_sizes, int n_in,
                              void* d_out, int out_size, void* d_ws, size_t ws_size,
                              hipStream_t stream) {
    const float* X = (const float*)d_in[0];
    const int*   Y = (const int*)d_in[1];
    const float* P = (const float*)d_in[2];
    float* out = (float*)d_out;
    float* partials = (float*)d_ws;   // 512 floats

    crf_fused<<<NB / NIPB, 320, 0, stream>>>(X, Y, P, partials);
    crf_reduce2<<<1, 256, 0, stream>>>(partials, out, NB / NIPB);
}